// Round 11
// baseline (1054.540 us; speedup 1.0000x reference)
//
#include <hip/hip_runtime.h>
#include <hip/hip_bf16.h>

typedef __bf16 bf16_t;
typedef __bf16 bf16x4 __attribute__((ext_vector_type(4)));
typedef __bf16 bf16x8 __attribute__((ext_vector_type(8)));
typedef float  f32x4  __attribute__((ext_vector_type(4)));

constexpr int T_ = 2048, H_ = 2048, I_ = 5632, E_ = 8, S_ = T_ * 2;

// ---- workspace layout (bytes) ----
constexpr size_t OFF_HB    = 0;                                   // bf16 hidden  [T][H]
constexpr size_t OFF_HOUT  = OFF_HB    + (size_t)T_ * H_ * 2;     // bf16 h       [S][I]
constexpr size_t OFF_DPART = OFF_HOUT  + (size_t)S_ * I_ * 2;     // f32 downpart [S][H]
constexpr size_t OFF_TOS   = OFF_DPART + (size_t)S_ * H_ * 4;     // int token_of_slot[S]
constexpr size_t OFF_SOT   = OFF_TOS   + (size_t)S_ * 4;          // int slot_of_tk[T*2]
constexpr size_t OFF_TKI   = OFF_SOT   + (size_t)S_ * 4;          // int topk_idx[T*2]
constexpr size_t OFF_TKW   = OFF_TKI   + (size_t)S_ * 4;          // f32 topk_w[T*2]
constexpr size_t OFF_CNT   = OFF_TKW   + (size_t)S_ * 4;          // int counts[E]
constexpr size_t OFF_OFFS  = OFF_CNT   + 64;                      // int offs[E]
constexpr size_t OFF_CUR   = OFF_OFFS  + 64;                      // int cursor[E]

// async global->LDS, 16B per lane. LDS dest = wave-uniform base + lane*16 (HW).
__device__ __forceinline__ void gload16(const void* g, void* l) {
  __builtin_amdgcn_global_load_lds(
      (const __attribute__((address_space(1))) void*)g,
      (__attribute__((address_space(3))) void*)l, 16, 0, 0);
}

// asm-pinned global load: volatile + "memory" -> cannot be sunk/remat'd by the scheduler.
__device__ __forceinline__ void gld4(f32x4& d, const float* p) {
  asm volatile("global_load_dwordx4 %0, %1, off" : "=&v"(d) : "v"(p) : "memory");
}

__device__ __forceinline__ bf16x8 cvt8(f32x4 a, f32x4 b) {
  bf16x8 r;
  r[0]=(bf16_t)a[0]; r[1]=(bf16_t)a[1]; r[2]=(bf16_t)a[2]; r[3]=(bf16_t)a[3];
  r[4]=(bf16_t)b[0]; r[5]=(bf16_t)b[1]; r[6]=(bf16_t)b[2]; r[7]=(bf16_t)b[3];
  return r;
}
__device__ __forceinline__ bf16x4 cvt4v(f32x4 a) {
  bf16x4 r; r[0]=(bf16_t)a[0]; r[1]=(bf16_t)a[1]; r[2]=(bf16_t)a[2]; r[3]=(bf16_t)a[3];
  return r;
}

#define SBAR() do { __builtin_amdgcn_s_barrier(); __builtin_amdgcn_sched_barrier(0); } while (0)
#define WAITV(N) do { asm volatile("s_waitcnt vmcnt(" #N ")" ::: "memory"); \
                      __builtin_amdgcn_sched_barrier(0); } while (0)
#define WAITVL(N) do { asm volatile("s_waitcnt vmcnt(" #N ") lgkmcnt(0)" ::: "memory"); \
                       __builtin_amdgcn_sched_barrier(0); } while (0)

// ================= router: logits, softmax, top-2, bf16 convert =================
__global__ __launch_bounds__(256)
void router_kernel(const float* __restrict__ hs, const float* __restrict__ gw,
                   int* __restrict__ tki, float* __restrict__ tkw,
                   int* __restrict__ counts, bf16_t* __restrict__ hb)
{
  const int t = blockIdx.x;
  const int tid = threadIdx.x;
  const int lane = tid & 63, wid = tid >> 6;
  const float* hrow = hs + (size_t)t * H_;
  const int c0 = tid * 8;
  float4 h0 = *(const float4*)(hrow + c0);
  float4 h1 = *(const float4*)(hrow + c0 + 4);
  bf16x8 hv;
  hv[0]=(bf16_t)h0.x; hv[1]=(bf16_t)h0.y; hv[2]=(bf16_t)h0.z; hv[3]=(bf16_t)h0.w;
  hv[4]=(bf16_t)h1.x; hv[5]=(bf16_t)h1.y; hv[6]=(bf16_t)h1.z; hv[7]=(bf16_t)h1.w;
  *(bf16x8*)(hb + (size_t)t * H_ + c0) = hv;

  float acc[E_];
  #pragma unroll
  for (int e = 0; e < E_; ++e) {
    const float* g = gw + (size_t)e * H_ + c0;
    float4 g0 = *(const float4*)(g);
    float4 g1 = *(const float4*)(g + 4);
    acc[e] = h0.x*g0.x + h0.y*g0.y + h0.z*g0.z + h0.w*g0.w
           + h1.x*g1.x + h1.y*g1.y + h1.z*g1.z + h1.w*g1.w;
  }
  #pragma unroll
  for (int e = 0; e < E_; ++e)
    #pragma unroll
    for (int o = 32; o > 0; o >>= 1)
      acc[e] += __shfl_down(acc[e], o);
  __shared__ float red[4][E_];
  if (lane == 0)
    #pragma unroll
    for (int e = 0; e < E_; ++e) red[wid][e] = acc[e];
  __syncthreads();
  if (tid == 0) {
    float l[E_];
    #pragma unroll
    for (int e = 0; e < E_; ++e) l[e] = red[0][e] + red[1][e] + red[2][e] + red[3][e];
    float m = l[0];
    #pragma unroll
    for (int e = 1; e < E_; ++e) m = fmaxf(m, l[e]);
    float p[E_]; float s = 0.f;
    #pragma unroll
    for (int e = 0; e < E_; ++e) { p[e] = __expf(l[e] - m); s += p[e]; }
    int i1 = 0;
    #pragma unroll
    for (int e = 1; e < E_; ++e) if (l[e] > l[i1]) i1 = e;
    int i2 = (i1 == 0) ? 1 : 0;
    #pragma unroll
    for (int e = 0; e < E_; ++e) if (e != i1 && l[e] > l[i2]) i2 = e;
    tki[2*t] = i1; tki[2*t+1] = i2;
    tkw[2*t] = p[i1] / s; tkw[2*t+1] = p[i2] / s;
    atomicAdd(&counts[i1], 1);
    atomicAdd(&counts[i2], 1);
  }
}

// ================= scan: expert offsets + slot lists =================
__global__ void scan_kernel(const int* __restrict__ counts, const int* __restrict__ tki,
                            int* __restrict__ offs, int* __restrict__ cursor,
                            int* __restrict__ tos, int* __restrict__ sot)
{
  if (threadIdx.x == 0) {
    int run = 0;
    for (int e = 0; e < E_; ++e) { offs[e] = run; cursor[e] = run; run += counts[e]; }
  }
  __syncthreads();
  for (int t = threadIdx.x; t < T_; t += blockDim.x) {
    #pragma unroll
    for (int k = 0; k < 2; ++k) {
      int e = tki[2*t + k];
      int s = atomicAdd(&cursor[e], 1);
      tos[s] = t;
      sot[2*t + k] = s;
    }
  }
}

// ================= GEMM1: gathered hidden x w1^T, dual (gate,up), fused silu*mul =================
// r10 layout (0 conflicts) + TRUE counted-vmcnt pipeline (T3/T4):
//   raw s_barrier, never vmcnt(0) in main loop; B global->reg loads depth-2 (full step in
//   flight ACROSS the barrier); A global_load_lds depth-1. One barrier per K-step.
// Per-step wait ledger (this wave, oldest->newest): [B(t+1)x2 | A(t+1)x2 | B(t+2)x2]
//   after compute: vmcnt(4) -> B(t+1) landed; writeB; vmcnt(2)+lgkm(0) -> A landed; s_barrier.
constexpr int G1_BUF = 16384 + 8192;   // A 16KB + B bf16 8KB; dbuf 48KB

__global__ __launch_bounds__(512, 4)
void gemm1_kernel(const bf16_t* __restrict__ hb, const float* __restrict__ w1,
                  const int* __restrict__ tos, const int* __restrict__ offs,
                  const int* __restrict__ counts, bf16_t* __restrict__ hout)
{
  const int bid = blockIdx.x;
  const int e   = bid & 7;
  const int idx = bid >> 3;          // 4 mt x 88 nt
  const int mt  = idx & 3;
  const int nt  = idx >> 2;

  const int cnt = counts[e];
  const int m0 = mt * 256;
  if (m0 >= cnt) return;
  const int off = offs[e];
  const int n0 = nt * 64;

  const float* Wg = w1 + (size_t)e * (2 * (size_t)I_ * H_) + (size_t)n0 * H_;

  __shared__ char smem[2 * G1_BUF];

  const int tid = threadIdx.x;
  const int lane = tid & 63, wid = tid >> 6;   // 8 waves
  const int wm = wid >> 1, wn = wid & 1;       // 4M x 2N
  const int l15 = lane & 15, l4 = lane >> 4;

  // --- A staging (depth-1): 16 chunks of 1KB (8 pairs x 128B); wave stages q = wid*2+{0,1}.
  const bf16_t* agp[2]; int aoff[2];
  #pragma unroll
  for (int i = 0; i < 2; ++i) {
    int q = wid * 2 + i;
    int w = (lane & 7) ^ ((lane >> 3) & 7);
    int row = 2 * (q * 8 + (lane >> 3)) + (w >> 2);
    int slot = off + m0 + row, mx = off + cnt - 1;
    if (slot > mx) slot = mx;
    agp[i]  = hb + (size_t)tos[slot] * H_ + (w & 3) * 8;
    aoff[i] = q * 1024;
  }
  auto stageA = [&](int b, int t) {
    char* ab = smem + b * G1_BUF;
    #pragma unroll
    for (int i = 0; i < 2; ++i) gload16(agp[i] + t * 32, ab + aoff[i]);
  };

  // --- B: 512 entries, 1/thread; p=tid>>3, phys=tid&7, wanted=phys^(p&7); n=2p+(w>>2).
  const int bp = tid >> 3, bw = (tid & 7) ^ (bp & 7);
  const int bn = 2 * bp + (bw >> 2);
  const size_t brow = (bn < 64) ? (size_t)bn : (size_t)(I_ + bn - 64);
  const float* bsrc = Wg + brow * H_ + (bw & 3) * 8;

  f32x4 b0x, b0y, b1x, b1y;          // two depth sets (static names, rule #20)

  f32x4 accg[4][2], accu[4][2];
  #pragma unroll
  for (int mi = 0; mi < 4; ++mi)
    #pragma unroll
    for (int ni = 0; ni < 2; ++ni) {
      accg[mi][ni] = f32x4{0.f,0.f,0.f,0.f};
      accu[mi][ni] = f32x4{0.f,0.f,0.f,0.f};
    }

  const int phys = ((((l15 & 1) << 2) | l4) ^ ((l15 >> 1) & 7)) * 16;

  auto compute = [&](int b) {
    const char* ab = smem + b * G1_BUF;
    const char* bb = ab + 16384;
    bf16x8 bgf[2], buf2[2];
    #pragma unroll
    for (int ni = 0; ni < 2; ++ni) {
      int pb = wn * 16 + ni * 8 + (l15 >> 1);
      bgf[ni]  = *(const bf16x8*)(bb + pb * 128 + phys);
      buf2[ni] = *(const bf16x8*)(bb + (pb + 32) * 128 + phys);
    }
    #pragma unroll
    for (int mi = 0; mi < 4; ++mi) {
      int pr = wm * 32 + mi * 8 + (l15 >> 1);
      bf16x8 af = *(const bf16x8*)(ab + pr * 128 + phys);
      accg[mi][0] = __builtin_amdgcn_mfma_f32_16x16x32_bf16(af, bgf[0],  accg[mi][0], 0, 0, 0);
      accg[mi][1] = __builtin_amdgcn_mfma_f32_16x16x32_bf16(af, bgf[1],  accg[mi][1], 0, 0, 0);
      accu[mi][0] = __builtin_amdgcn_mfma_f32_16x16x32_bf16(af, buf2[0], accu[mi][0], 0, 0, 0);
      accu[mi][1] = __builtin_amdgcn_mfma_f32_16x16x32_bf16(af, buf2[1], accu[mi][1], 0, 0, 0);
    }
  };

  constexpr int NK = H_ / 32;   // 64
  int cur = 0;

  // prologue: A(0) + B(0),B(1); publish buf0 with B(1) left in flight
  stageA(0, 0);
  gld4(b0x, bsrc);      gld4(b0y, bsrc + 4);
  gld4(b1x, bsrc + 32); gld4(b1y, bsrc + 36);
  WAITV(2);                                   // A(0)+B(0) done; B(1) flying
  *(bf16x8*)(smem + 16384 + tid * 16) = cvt8(b0x, b0y);
  asm volatile("s_waitcnt lgkmcnt(0)" ::: "memory");
  SBAR();

  auto body = [&](int t, f32x4& lx, f32x4& ly, f32x4& wx, f32x4& wy) {
    stageA(cur ^ 1, t + 1);                   // A(t+1): 2 gloads
    gld4(lx, bsrc + (t + 2) * 32);            // B(t+2): 2 loads (stay in flight past barrier)
    gld4(ly, bsrc + (t + 2) * 32 + 4);
    compute(cur);
    WAITV(4);                                 // B(t+1) landed
    *(bf16x8*)(smem + (cur ^ 1) * G1_BUF + 16384 + tid * 16) = cvt8(wx, wy);
    WAITVL(2);                                // A(t+1) landed (B(t+2) still flying)
    SBAR();                                   // publish buf cur^1
    cur ^= 1;
  };
  for (int t = 0; t < NK - 2; t += 2) {       // 62 iterations (even)
    body(t,     b0x, b0y, b1x, b1y);
    body(t + 1, b1x, b1y, b0x, b0y);
  }
  // t = NK-2: no new B issue
  stageA(cur ^ 1, NK - 1);
  compute(cur);
  WAITV(2);                                   // B(NK-1) landed
  *(bf16x8*)(smem + (cur ^ 1) * G1_BUF + 16384 + tid * 16) = cvt8(b1x, b1y);
  WAITVL(0);
  SBAR();
  cur ^= 1;
  compute(cur);                               // t = NK-1

  // epilogue: silu(g)*u -> bf16 h[slot][i]
  #pragma unroll
  for (int mi = 0; mi < 4; ++mi)
    #pragma unroll
    for (int ni = 0; ni < 2; ++ni)
      #pragma unroll
      for (int j = 0; j < 4; ++j) {
        int rel = wm*64 + mi*16 + l4*4 + j;
        if (m0 + rel < cnt) {
          int col = n0 + wn*32 + ni*16 + l15;
          float g = accg[mi][ni][j];
          float u = accu[mi][ni][j];
          float hvv = (g / (1.0f + __expf(-g))) * u;
          hout[(size_t)(off + m0 + rel) * I_ + col] = (bf16_t)hvv;
        }
      }
}

// ================= GEMM2: h x w2^T -> per-slot partial (f32) =================
// Same pipeline; ALL 512 threads stage B (1x dwordx4 + ds_write_b64 each) so wait
// counts are wave-uniform. Ledger: [B(t+1)x1 | A(t+1)x2 | B(t+2)x1] -> vmcnt(3) / vmcnt(1).
constexpr int G2_BUF = 16384 + 4096;   // A 16KB + B bf16 4KB; dbuf 40KB

__global__ __launch_bounds__(512, 4)
void gemm2_kernel(const bf16_t* __restrict__ hbuf, const float* __restrict__ w2,
                  const int* __restrict__ offs, const int* __restrict__ counts,
                  float* __restrict__ dpart)
{
  const int bid = blockIdx.x;
  const int e   = bid & 7;
  const int idx = bid >> 3;          // 4 mt x 32 nt
  const int mt  = idx & 3;
  const int nt  = idx >> 2;

  const int cnt = counts[e];
  const int m0 = mt * 256;
  if (m0 >= cnt) return;
  const int off = offs[e];
  const int n0 = nt * 64;
  const float* W = w2 + (size_t)e * ((size_t)H_ * I_) + (size_t)n0 * I_;

  __shared__ char smem[2 * G2_BUF];

  const int tid = threadIdx.x;
  const int lane = tid & 63, wid = tid >> 6;
  const int wm = wid >> 1, wn = wid & 1;
  const int l15 = lane & 15, l4 = lane >> 4;

  const bf16_t* agp[2]; int aoff[2];
  #pragma unroll
  for (int i = 0; i < 2; ++i) {
    int q = wid * 2 + i;
    int w = (lane & 7) ^ ((lane >> 3) & 7);
    int row = 2 * (q * 8 + (lane >> 3)) + (w >> 2);
    int slot = off + m0 + row, mx = off + cnt - 1;
    if (slot > mx) slot = mx;
    agp[i]  = hbuf + (size_t)slot * I_ + (w & 3) * 8;
    aoff[i] = q * 1024;
  }
  auto stageA = [&](int b, int t) {
    char* ab = smem + b * G2_BUF;
    #pragma unroll
    for (int i = 0; i < 2; ++i) gload16(agp[i] + t * 32, ab + aoff[i]);
  };

  // B: 256 slots x 16B as 512 half-slots of 8B; thread -> slot tid>>1, half tid&1.
  const int s2 = tid >> 1, h2 = tid & 1;
  const int p2 = s2 >> 3, w2s = (s2 & 7) ^ (p2 & 7);
  const int bn2 = 2 * p2 + (w2s >> 2);
  const float* bsrc = W + (size_t)bn2 * I_ + (w2s & 3) * 8 + h2 * 4;
  const int bldsoff = 16384 + s2 * 16 + h2 * 8;

  f32x4 b0, b1;                      // depth-2 sets

  f32x4 acc[4][2];
  #pragma unroll
  for (int mi = 0; mi < 4; ++mi)
    #pragma unroll
    for (int ni = 0; ni < 2; ++ni) acc[mi][ni] = f32x4{0.f,0.f,0.f,0.f};

  const int phys = ((((l15 & 1) << 2) | l4) ^ ((l15 >> 1) & 7)) * 16;

  auto compute = [&](int b) {
    const char* ab = smem + b * G2_BUF;
    const char* bb = ab + 16384;
    bf16x8 bf[2];
    #pragma unroll
    for (int ni = 0; ni < 2; ++ni) {
      int pb = wn * 16 + ni * 8 + (l15 >> 1);
      bf[ni] = *(const bf16x8*)(bb + pb * 128 + phys);
    }
    #pragma unroll
    for (int mi = 0; mi < 4; ++mi) {
      int pr = wm * 32 + mi * 8 + (l15 >> 1);
      bf16x8 af = *(const bf16x8*)(ab + pr * 128 + phys);
      acc[mi][0] = __builtin_amdgcn_mfma_f32_16x16x32_bf16(af, bf[0], acc[mi][0], 0, 0, 0);
      acc[mi][1] = __builtin_amdgcn_mfma_f32_16x16x32_bf16(af, bf[1], acc[mi][1], 0, 0, 0);
    }
  };

  constexpr int NK = I_ / 32;   // 176
  int cur = 0;

  stageA(0, 0);
  gld4(b0, bsrc);
  gld4(b1, bsrc + 32);
  WAITV(1);                                   // A(0)+B(0) done; B(1) flying
  *(bf16x4*)(smem + bldsoff) = cvt4v(b0);
  asm volatile("s_waitcnt lgkmcnt(0)" ::: "memory");
  SBAR();

  auto body = [&](int t, f32x4& lx, f32x4& wx) {
    stageA(cur ^ 1, t + 1);
    gld4(lx, bsrc + (t + 2) * 32);
    compute(cur);
    WAITV(3);                                 // B(t+1) landed
    *(bf16x4*)(smem + (cur ^ 1) * G2_BUF + bldsoff) = cvt4v(wx);
    WAITVL(1);                                // A(t+1) landed; B(t+2) flying
    SBAR();
    cur ^= 1;
  };
  for (int t = 0; t < NK - 2; t += 2) {       // 174 iterations (even)
    body(t,     b0, b1);
    body(t + 1, b1, b0);
  }
  stageA(cur ^ 1, NK - 1);
  compute(cur);
  WAITV(2);                                   // B(NK-1) landed
  *(bf16x4*)(smem + (cur ^ 1) * G2_BUF + bldsoff) = cvt4v(b1);
  WAITVL(0);
  SBAR();
  cur ^= 1;
  compute(cur);

  #pragma unroll
  for (int mi = 0; mi < 4; ++mi)
    #pragma unroll
    for (int ni = 0; ni < 2; ++ni)
      #pragma unroll
      for (int j = 0; j < 4; ++j) {
        int rel = wm*64 + mi*16 + l4*4 + j;
        if (m0 + rel < cnt) {
          int col = n0 + wn*32 + ni*16 + l15;
          dpart[(size_t)(off + m0 + rel) * H_ + col] = acc[mi][ni][j];
        }
      }
}

// ================= combine: out[t] = w0*d[s0] + w1*d[s1] =================
__global__ __launch_bounds__(256)
void combine_kernel(const float* __restrict__ dpart, const int* __restrict__ sot,
                    const float* __restrict__ tkw, float* __restrict__ out)
{
  int idx = blockIdx.x * 256 + threadIdx.x;     // T*H/4 total
  int t = idx >> 9;                              // H/4 = 512
  int c = (idx & 511) * 4;
  float wA = tkw[2*t], wB = tkw[2*t+1];
  int sA = sot[2*t], sB = sot[2*t+1];
  float4 a = *(const float4*)(dpart + (size_t)sA * H_ + c);
  float4 b = *(const float4*)(dpart + (size_t)sB * H_ + c);
  float4 o;
  o.x = wA*a.x + wB*b.x; o.y = wA*a.y + wB*b.y;
  o.z = wA*a.z + wB*b.z; o.w = wA*a.w + wB*b.w;
  *(float4*)(out + (size_t)t * H_ + c) = o;
}

extern "C" void kernel_launch(void* const* d_in, const int* in_sizes, int n_in,
                              void* d_out, int out_size, void* d_ws, size_t ws_size,
                              hipStream_t stream) {
  const float* hs = (const float*)d_in[0];
  const float* gw = (const float*)d_in[1];
  const float* w1 = (const float*)d_in[2];
  const float* w2 = (const float*)d_in[3];
  float* out = (float*)d_out;
  char* ws = (char*)d_ws;

  bf16_t* hb    = (bf16_t*)(ws + OFF_HB);
  bf16_t* hout  = (bf16_t*)(ws + OFF_HOUT);
  float*  dpart = (float*) (ws + OFF_DPART);
  int*    tos   = (int*)   (ws + OFF_TOS);
  int*    sot   = (int*)   (ws + OFF_SOT);
  int*    tki   = (int*)   (ws + OFF_TKI);
  float*  tkw   = (float*) (ws + OFF_TKW);
  int*    cnt   = (int*)   (ws + OFF_CNT);
  int*    offp  = (int*)   (ws + OFF_OFFS);
  int*    curp  = (int*)   (ws + OFF_CUR);

  hipMemsetAsync(ws + OFF_CNT, 0, 64, stream);   // zero expert counts each call

  router_kernel<<<T_, 256, 0, stream>>>(hs, gw, tki, tkw, cnt, hb);
  scan_kernel<<<1, 256, 0, stream>>>(cnt, tki, offp, curp, tos, sot);
  gemm1_kernel<<<4 * (2 * I_ / 128) * E_, 512, 0, stream>>>(hb, w1, tos, offp, cnt, hout);  // 4mt x 88nt x 8e
  gemm2_kernel<<<4 * (H_ / 64) * E_, 512, 0, stream>>>(hout, w2, offp, cnt, dpart);         // 4mt x 32nt x 8e
  combine_kernel<<<(T_ * H_ / 4) / 256, 256, 0, stream>>>(dpart, sot, tkw, out);
}

// Round 12
// 971.671 us; speedup vs baseline: 1.0853x; 1.0853x over previous
//
#include <hip/hip_runtime.h>
#include <hip/hip_bf16.h>

typedef __bf16 bf16_t;
typedef __bf16 bf16x4 __attribute__((ext_vector_type(4)));
typedef __bf16 bf16x8 __attribute__((ext_vector_type(8)));
typedef float  f32x4  __attribute__((ext_vector_type(4)));

constexpr int T_ = 2048, H_ = 2048, I_ = 5632, E_ = 8, S_ = T_ * 2;

// ---- workspace layout (bytes) ----
constexpr size_t OFF_HB    = 0;                                   // bf16 hidden  [T][H]
constexpr size_t OFF_HOUT  = OFF_HB    + (size_t)T_ * H_ * 2;     // bf16 h       [S][I]
constexpr size_t OFF_DPART = OFF_HOUT  + (size_t)S_ * I_ * 2;     // f32 downpart [S][H]
constexpr size_t OFF_TOS   = OFF_DPART + (size_t)S_ * H_ * 4;     // int token_of_slot[S]
constexpr size_t OFF_SOT   = OFF_TOS   + (size_t)S_ * 4;          // int slot_of_tk[T*2]
constexpr size_t OFF_TKI   = OFF_SOT   + (size_t)S_ * 4;          // int topk_idx[T*2]
constexpr size_t OFF_TKW   = OFF_TKI   + (size_t)S_ * 4;          // f32 topk_w[T*2]
constexpr size_t OFF_CNT   = OFF_TKW   + (size_t)S_ * 4;          // int counts[E]
constexpr size_t OFF_OFFS  = OFF_CNT   + 64;                      // int offs[E]
constexpr size_t OFF_CUR   = OFF_OFFS  + 64;                      // int cursor[E]
constexpr size_t OFF_HG    = OFF_CUR   + 64;                      // bf16 gathered hidden [S][H] (16MB)

// async global->LDS, 16B per lane. LDS dest = wave-uniform base + lane*16 (HW).
__device__ __forceinline__ void gload16(const void* g, void* l) {
  __builtin_amdgcn_global_load_lds(
      (const __attribute__((address_space(1))) void*)g,
      (__attribute__((address_space(3))) void*)l, 16, 0, 0);
}

// asm-pinned global load: volatile + "memory" -> cannot be sunk/remat'd.
__device__ __forceinline__ void gld4(f32x4& d, const float* p) {
  asm volatile("global_load_dwordx4 %0, %1, off" : "=&v"(d) : "v"(p) : "memory");
}

__device__ __forceinline__ bf16x4 cvt4v(f32x4 a) {
  bf16x4 r; r[0]=(bf16_t)a[0]; r[1]=(bf16_t)a[1]; r[2]=(bf16_t)a[2]; r[3]=(bf16_t)a[3];
  return r;
}

#define SBAR() do { __builtin_amdgcn_s_barrier(); __builtin_amdgcn_sched_barrier(0); } while (0)
#define WAITV(N) do { asm volatile("s_waitcnt vmcnt(" #N ")" ::: "memory"); \
                      __builtin_amdgcn_sched_barrier(0); } while (0)
#define WAITL0() do { asm volatile("s_waitcnt lgkmcnt(0)" ::: "memory"); \
                      __builtin_amdgcn_sched_barrier(0); } while (0)

// ================= router: logits, softmax, top-2, bf16 convert =================
__global__ __launch_bounds__(256)
void router_kernel(const float* __restrict__ hs, const float* __restrict__ gw,
                   int* __restrict__ tki, float* __restrict__ tkw,
                   int* __restrict__ counts, bf16_t* __restrict__ hb)
{
  const int t = blockIdx.x;
  const int tid = threadIdx.x;
  const int lane = tid & 63, wid = tid >> 6;
  const float* hrow = hs + (size_t)t * H_;
  const int c0 = tid * 8;
  float4 h0 = *(const float4*)(hrow + c0);
  float4 h1 = *(const float4*)(hrow + c0 + 4);
  bf16x8 hv;
  hv[0]=(bf16_t)h0.x; hv[1]=(bf16_t)h0.y; hv[2]=(bf16_t)h0.z; hv[3]=(bf16_t)h0.w;
  hv[4]=(bf16_t)h1.x; hv[5]=(bf16_t)h1.y; hv[6]=(bf16_t)h1.z; hv[7]=(bf16_t)h1.w;
  *(bf16x8*)(hb + (size_t)t * H_ + c0) = hv;

  float acc[E_];
  #pragma unroll
  for (int e = 0; e < E_; ++e) {
    const float* g = gw + (size_t)e * H_ + c0;
    float4 g0 = *(const float4*)(g);
    float4 g1 = *(const float4*)(g + 4);
    acc[e] = h0.x*g0.x + h0.y*g0.y + h0.z*g0.z + h0.w*g0.w
           + h1.x*g1.x + h1.y*g1.y + h1.z*g1.z + h1.w*g1.w;
  }
  #pragma unroll
  for (int e = 0; e < E_; ++e)
    #pragma unroll
    for (int o = 32; o > 0; o >>= 1)
      acc[e] += __shfl_down(acc[e], o);
  __shared__ float red[4][E_];
  if (lane == 0)
    #pragma unroll
    for (int e = 0; e < E_; ++e) red[wid][e] = acc[e];
  __syncthreads();
  if (tid == 0) {
    float l[E_];
    #pragma unroll
    for (int e = 0; e < E_; ++e) l[e] = red[0][e] + red[1][e] + red[2][e] + red[3][e];
    float m = l[0];
    #pragma unroll
    for (int e = 1; e < E_; ++e) m = fmaxf(m, l[e]);
    float p[E_]; float s = 0.f;
    #pragma unroll
    for (int e = 0; e < E_; ++e) { p[e] = __expf(l[e] - m); s += p[e]; }
    int i1 = 0;
    #pragma unroll
    for (int e = 1; e < E_; ++e) if (l[e] > l[i1]) i1 = e;
    int i2 = (i1 == 0) ? 1 : 0;
    #pragma unroll
    for (int e = 0; e < E_; ++e) if (e != i1 && l[e] > l[i2]) i2 = e;
    tki[2*t] = i1; tki[2*t+1] = i2;
    tkw[2*t] = p[i1] / s; tkw[2*t+1] = p[i2] / s;
    atomicAdd(&counts[i1], 1);
    atomicAdd(&counts[i2], 1);
  }
}

// ================= scan: expert offsets + slot lists =================
__global__ void scan_kernel(const int* __restrict__ counts, const int* __restrict__ tki,
                            int* __restrict__ offs, int* __restrict__ cursor,
                            int* __restrict__ tos, int* __restrict__ sot)
{
  if (threadIdx.x == 0) {
    int run = 0;
    for (int e = 0; e < E_; ++e) { offs[e] = run; cursor[e] = run; run += counts[e]; }
  }
  __syncthreads();
  for (int t = threadIdx.x; t < T_; t += blockDim.x) {
    #pragma unroll
    for (int k = 0; k < 2; ++k) {
      int e = tki[2*t + k];
      int s = atomicAdd(&cursor[e], 1);
      tos[s] = t;
      sot[2*t + k] = s;
    }
  }
}

// ================= gather: hg[slot] = hb[tos[slot]]  (one 4KB row per block) =================
__global__ __launch_bounds__(256)
void gather_kernel(const bf16_t* __restrict__ hb, const int* __restrict__ tos,
                   bf16_t* __restrict__ hg)
{
  const int slot = blockIdx.x;
  const int tok  = tos[slot];
  const int c = threadIdx.x * 8;
  *(bf16x8*)(hg + (size_t)slot * H_ + c) = *(const bf16x8*)(hb + (size_t)tok * H_ + c);
}

// ================= GEMM1: hg x w1^T, dual (gate,up), fused silu*mul =================
// Depth-2 EVERYWHERE (T3/T4): at step t issue A(t+2) [gload_lds, 3 LDS bufs] and
// B(t+2) [coalesced dwordx4 -> regs, 2 sets]; consume step t; wait only t-1's items
// (vmcnt(4)); writeB(t+1); lgkm0; raw s_barrier. Never vmcnt(0) in loop: every load
// has a FULL step (~800cyc) in flight across the barrier.
// BM=256, BN=64, BK=32, 512 thr (8 waves, 4Mx2N). LDS: 3x16KB A + 2x8KB B = 64KB.
// Layouts: pair-packed 128B rows, phys slot = wanted ^ (pair&7) (measured 0 conflicts).
constexpr int G1_ABUF = 16384, G1_BBUF = 8192;
constexpr int G1_BBASE = 3 * G1_ABUF;

__global__ __launch_bounds__(512, 4)
void gemm1_kernel(const bf16_t* __restrict__ hg, const float* __restrict__ w1,
                  const int* __restrict__ offs, const int* __restrict__ counts,
                  bf16_t* __restrict__ hout)
{
  const int bid = blockIdx.x;
  const int e   = bid & 7;
  const int idx = bid >> 3;          // 4 mt x 88 nt
  const int mt  = idx & 3;
  const int nt  = idx >> 2;

  const int cnt = counts[e];
  const int m0 = mt * 256;
  if (m0 >= cnt) return;
  const int off = offs[e];
  const int n0 = nt * 64;

  const float* Wg = w1 + (size_t)e * (2 * (size_t)I_ * H_) + (size_t)n0 * H_;

  __shared__ char smem[3 * G1_ABUF + 2 * G1_BBUF];   // 64KB

  const int tid = threadIdx.x;
  const int lane = tid & 63, wid = tid >> 6;   // 8 waves
  const int wm = wid >> 1, wn = wid & 1;       // 4M x 2N
  const int l15 = lane & 15, l4 = lane >> 4;

  // --- A staging: 16 chunks of 1KB (8 pairs x 128B); wave stages q = wid*2+{0,1}.
  const bf16_t* agp[2]; int aoff[2];
  #pragma unroll
  for (int i = 0; i < 2; ++i) {
    int q = wid * 2 + i;
    int w = (lane & 7) ^ ((lane >> 3) & 7);
    int row = 2 * (q * 8 + (lane >> 3)) + (w >> 2);
    int slot = off + m0 + row, mx = off + cnt - 1;
    if (slot > mx) slot = mx;                  // clamp pad rows (masked at store)
    agp[i]  = hg + (size_t)slot * H_ + (w & 3) * 8;
    aoff[i] = q * 1024;
  }
  auto stageA = [&](int ab, int t) {
    char* p = smem + ab * G1_ABUF;
    #pragma unroll
    for (int i = 0; i < 2; ++i) gload16(agp[i] + t * 32, p + aoff[i]);
  };

  // --- B: coalesced reads. thread t: f32 row r=t>>3 (gate) and I_+r (up), seg s=t&7 (16B).
  // LDS n: gate r, up 64+r; pair p=n>>1, wanted w=(n&1)*4+(s>>1), phys=w^(p&7),
  // byte = p*128 + phys*16 + (s&1)*8.
  const int brow = tid >> 3, bseg = tid & 7;
  const float* bgsrc = Wg + (size_t)brow * H_ + bseg * 4;
  const float* busrc = Wg + (size_t)(I_ + brow) * H_ + bseg * 4;
  int gOff, uOff;
  {
    int ng = brow, nu = 64 + brow;
    int wg_ = (ng & 1) * 4 + (bseg >> 1), wu_ = (nu & 1) * 4 + (bseg >> 1);
    gOff = (ng >> 1) * 128 + (wg_ ^ ((ng >> 1) & 7)) * 16 + (bseg & 1) * 8;
    uOff = (nu >> 1) * 128 + (wu_ ^ ((nu >> 1) & 7)) * 16 + (bseg & 1) * 8;
  }
  f32x4 b0g, b0u, b1g, b1u;          // two depth sets (static names)

  f32x4 accg[4][2], accu[4][2];
  #pragma unroll
  for (int mi = 0; mi < 4; ++mi)
    #pragma unroll
    for (int ni = 0; ni < 2; ++ni) {
      accg[mi][ni] = f32x4{0.f,0.f,0.f,0.f};
      accu[mi][ni] = f32x4{0.f,0.f,0.f,0.f};
    }

  const int phys = ((((l15 & 1) << 2) | l4) ^ ((l15 >> 1) & 7)) * 16;

  auto compute = [&](int ab, int blds) {
    const char* ap = smem + ab * G1_ABUF;
    const char* bp2 = smem + G1_BBASE + blds * G1_BBUF;
    bf16x8 bgf[2], buf2[2];
    #pragma unroll
    for (int ni = 0; ni < 2; ++ni) {
      int pb = wn * 16 + ni * 8 + (l15 >> 1);
      bgf[ni]  = *(const bf16x8*)(bp2 + pb * 128 + phys);
      buf2[ni] = *(const bf16x8*)(bp2 + (pb + 32) * 128 + phys);
    }
    #pragma unroll
    for (int mi = 0; mi < 4; ++mi) {
      int pr = wm * 32 + mi * 8 + (l15 >> 1);
      bf16x8 af = *(const bf16x8*)(ap + pr * 128 + phys);
      accg[mi][0] = __builtin_amdgcn_mfma_f32_16x16x32_bf16(af, bgf[0],  accg[mi][0], 0, 0, 0);
      accg[mi][1] = __builtin_amdgcn_mfma_f32_16x16x32_bf16(af, bgf[1],  accg[mi][1], 0, 0, 0);
      accu[mi][0] = __builtin_amdgcn_mfma_f32_16x16x32_bf16(af, buf2[0], accu[mi][0], 0, 0, 0);
      accu[mi][1] = __builtin_amdgcn_mfma_f32_16x16x32_bf16(af, buf2[1], accu[mi][1], 0, 0, 0);
    }
  };
  auto writeB = [&](int blds, f32x4& g, f32x4& u) {
    char* bp2 = smem + G1_BBASE + blds * G1_BBUF;
    *(bf16x4*)(bp2 + gOff) = cvt4v(g);
    *(bf16x4*)(bp2 + uOff) = cvt4v(u);
  };

  constexpr int NK = H_ / 32;   // 64 (even)
  // prologue: A(0),B(0),A(1),B(1) -> wait oldest 4 -> publish step-0 state
  stageA(0, 0);
  gld4(b0g, bgsrc); gld4(b0u, busrc);
  stageA(1, 1);
  gld4(b1g, bgsrc + 32); gld4(b1u, busrc + 32);
  WAITV(4);                                    // A(0)+B(0) landed; A(1),B(1) flying
  writeB(0, b0g, b0u);
  WAITL0();
  SBAR();

  int aR = 0, aN = 1, aW = 2;
  for (int t = 0; t < NK - 2; t += 2) {
    // ---- even step t: load set0 <- k(t+2); write set1 (k(t+1)) ----
    stageA(aW, t + 2);
    gld4(b0g, bgsrc + (t + 2) * 32); gld4(b0u, busrc + (t + 2) * 32);
    compute(aR, 0);
    WAITV(4);                                  // t-1's A,B landed
    writeB(1, b1g, b1u);
    WAITL0();
    SBAR();
    { int tmp = aR; aR = aN; aN = aW; aW = tmp; }
    // ---- odd step t+1: load set1 <- k(t+3); write set0 (k(t+2)) ----
    stageA(aW, t + 3);
    gld4(b1g, bgsrc + (t + 3) * 32); gld4(b1u, busrc + (t + 3) * 32);
    compute(aR, 1);
    WAITV(4);
    writeB(0, b0g, b0u);
    WAITL0();
    SBAR();
    { int tmp = aR; aR = aN; aN = aW; aW = tmp; }
  }
  // step NK-2 (even): nothing to issue; drain
  compute(aR, 0);
  WAITV(0);                                    // A(NK-1)+B(NK-1) landed
  writeB(1, b1g, b1u);
  WAITL0();
  SBAR();
  compute(aN, 1);                              // step NK-1

  // epilogue: silu(g)*u -> bf16 h[slot][i]
  #pragma unroll
  for (int mi = 0; mi < 4; ++mi)
    #pragma unroll
    for (int ni = 0; ni < 2; ++ni)
      #pragma unroll
      for (int j = 0; j < 4; ++j) {
        int rel = wm*64 + mi*16 + l4*4 + j;
        if (m0 + rel < cnt) {
          int col = n0 + wn*32 + ni*16 + l15;
          float g = accg[mi][ni][j];
          float u = accu[mi][ni][j];
          float hvv = (g / (1.0f + __expf(-g))) * u;
          hout[(size_t)(off + m0 + rel) * I_ + col] = (bf16_t)hvv;
        }
      }
}

// ================= GEMM2: h x w2^T -> per-slot partial (f32) =================
// Same depth-2 pipeline. B: 1 coalesced dwordx4/thread (row=t>>3 in [0,64), seg=t&7).
// Ledger/step: A x2 + B x1 = 3 -> WAITV(3). LDS: 3x16KB A + 2x4KB B = 56KB.
constexpr int G2_ABUF = 16384, G2_BBUF = 4096;
constexpr int G2_BBASE = 3 * G2_ABUF;

__global__ __launch_bounds__(512, 4)
void gemm2_kernel(const bf16_t* __restrict__ hbuf, const float* __restrict__ w2,
                  const int* __restrict__ offs, const int* __restrict__ counts,
                  float* __restrict__ dpart)
{
  const int bid = blockIdx.x;
  const int e   = bid & 7;
  const int idx = bid >> 3;          // 4 mt x 32 nt
  const int mt  = idx & 3;
  const int nt  = idx >> 2;

  const int cnt = counts[e];
  const int m0 = mt * 256;
  if (m0 >= cnt) return;
  const int off = offs[e];
  const int n0 = nt * 64;
  const float* W = w2 + (size_t)e * ((size_t)H_ * I_) + (size_t)n0 * I_;

  __shared__ char smem[3 * G2_ABUF + 2 * G2_BBUF];   // 56KB

  const int tid = threadIdx.x;
  const int lane = tid & 63, wid = tid >> 6;
  const int wm = wid >> 1, wn = wid & 1;
  const int l15 = lane & 15, l4 = lane >> 4;

  const bf16_t* agp[2]; int aoff[2];
  #pragma unroll
  for (int i = 0; i < 2; ++i) {
    int q = wid * 2 + i;
    int w = (lane & 7) ^ ((lane >> 3) & 7);
    int row = 2 * (q * 8 + (lane >> 3)) + (w >> 2);
    int slot = off + m0 + row, mx = off + cnt - 1;
    if (slot > mx) slot = mx;
    agp[i]  = hbuf + (size_t)slot * I_ + (w & 3) * 8;
    aoff[i] = q * 1024;
  }
  auto stageA = [&](int ab, int t) {
    char* p = smem + ab * G2_ABUF;
    #pragma unroll
    for (int i = 0; i < 2; ++i) gload16(agp[i] + t * 32, p + aoff[i]);
  };

  const int brow = tid >> 3, bseg = tid & 7;
  const float* bsrc = W + (size_t)brow * I_ + bseg * 4;
  int bOff;
  {
    int w_ = (brow & 1) * 4 + (bseg >> 1);
    bOff = (brow >> 1) * 128 + (w_ ^ ((brow >> 1) & 7)) * 16 + (bseg & 1) * 8;
  }
  f32x4 b0, b1;

  f32x4 acc[4][2];
  #pragma unroll
  for (int mi = 0; mi < 4; ++mi)
    #pragma unroll
    for (int ni = 0; ni < 2; ++ni) acc[mi][ni] = f32x4{0.f,0.f,0.f,0.f};

  const int phys = ((((l15 & 1) << 2) | l4) ^ ((l15 >> 1) & 7)) * 16;

  auto compute = [&](int ab, int blds) {
    const char* ap = smem + ab * G2_ABUF;
    const char* bp2 = smem + G2_BBASE + blds * G2_BBUF;
    bf16x8 bf[2];
    #pragma unroll
    for (int ni = 0; ni < 2; ++ni) {
      int pb = wn * 16 + ni * 8 + (l15 >> 1);
      bf[ni] = *(const bf16x8*)(bp2 + pb * 128 + phys);
    }
    #pragma unroll
    for (int mi = 0; mi < 4; ++mi) {
      int pr = wm * 32 + mi * 8 + (l15 >> 1);
      bf16x8 af = *(const bf16x8*)(ap + pr * 128 + phys);
      acc[mi][0] = __builtin_amdgcn_mfma_f32_16x16x32_bf16(af, bf[0], acc[mi][0], 0, 0, 0);
      acc[mi][1] = __builtin_amdgcn_mfma_f32_16x16x32_bf16(af, bf[1], acc[mi][1], 0, 0, 0);
    }
  };
  auto writeB = [&](int blds, f32x4& v) {
    *(bf16x4*)(smem + G2_BBASE + blds * G2_BBUF + bOff) = cvt4v(v);
  };

  constexpr int NK = I_ / 32;   // 176 (even)
  stageA(0, 0);
  gld4(b0, bsrc);
  stageA(1, 1);
  gld4(b1, bsrc + 32);
  WAITV(3);                                    // A(0)+B(0) landed
  writeB(0, b0);
  WAITL0();
  SBAR();

  int aR = 0, aN = 1, aW = 2;
  for (int t = 0; t < NK - 2; t += 2) {
    stageA(aW, t + 2);
    gld4(b0, bsrc + (t + 2) * 32);
    compute(aR, 0);
    WAITV(3);
    writeB(1, b1);
    WAITL0();
    SBAR();
    { int tmp = aR; aR = aN; aN = aW; aW = tmp; }
    stageA(aW, t + 3);
    gld4(b1, bsrc + (t + 3) * 32);
    compute(aR, 1);
    WAITV(3);
    writeB(0, b0);
    WAITL0();
    SBAR();
    { int tmp = aR; aR = aN; aN = aW; aW = tmp; }
  }
  compute(aR, 0);
  WAITV(0);
  writeB(1, b1);
  WAITL0();
  SBAR();
  compute(aN, 1);

  #pragma unroll
  for (int mi = 0; mi < 4; ++mi)
    #pragma unroll
    for (int ni = 0; ni < 2; ++ni)
      #pragma unroll
      for (int j = 0; j < 4; ++j) {
        int rel = wm*64 + mi*16 + l4*4 + j;
        if (m0 + rel < cnt) {
          int col = n0 + wn*32 + ni*16 + l15;
          dpart[(size_t)(off + m0 + rel) * H_ + col] = acc[mi][ni][j];
        }
      }
}

// ================= combine: out[t] = w0*d[s0] + w1*d[s1] =================
__global__ __launch_bounds__(256)
void combine_kernel(const float* __restrict__ dpart, const int* __restrict__ sot,
                    const float* __restrict__ tkw, float* __restrict__ out)
{
  int idx = blockIdx.x * 256 + threadIdx.x;     // T*H/4 total
  int t = idx >> 9;                              // H/4 = 512
  int c = (idx & 511) * 4;
  float wA = tkw[2*t], wB = tkw[2*t+1];
  int sA = sot[2*t], sB = sot[2*t+1];
  float4 a = *(const float4*)(dpart + (size_t)sA * H_ + c);
  float4 b = *(const float4*)(dpart + (size_t)sB * H_ + c);
  float4 o;
  o.x = wA*a.x + wB*b.x; o.y = wA*a.y + wB*b.y;
  o.z = wA*a.z + wB*b.z; o.w = wA*a.w + wB*b.w;
  *(float4*)(out + (size_t)t * H_ + c) = o;
}

extern "C" void kernel_launch(void* const* d_in, const int* in_sizes, int n_in,
                              void* d_out, int out_size, void* d_ws, size_t ws_size,
                              hipStream_t stream) {
  const float* hs = (const float*)d_in[0];
  const float* gw = (const float*)d_in[1];
  const float* w1 = (const float*)d_in[2];
  const float* w2 = (const float*)d_in[3];
  float* out = (float*)d_out;
  char* ws = (char*)d_ws;

  bf16_t* hb    = (bf16_t*)(ws + OFF_HB);
  bf16_t* hout  = (bf16_t*)(ws + OFF_HOUT);
  float*  dpart = (float*) (ws + OFF_DPART);
  int*    tos   = (int*)   (ws + OFF_TOS);
  int*    sot   = (int*)   (ws + OFF_SOT);
  int*    tki   = (int*)   (ws + OFF_TKI);
  float*  tkw   = (float*) (ws + OFF_TKW);
  int*    cnt   = (int*)   (ws + OFF_CNT);
  int*    offp  = (int*)   (ws + OFF_OFFS);
  int*    curp  = (int*)   (ws + OFF_CUR);
  bf16_t* hg    = (bf16_t*)(ws + OFF_HG);

  hipMemsetAsync(ws + OFF_CNT, 0, 64, stream);   // zero expert counts each call

  router_kernel<<<T_, 256, 0, stream>>>(hs, gw, tki, tkw, cnt, hb);
  scan_kernel<<<1, 256, 0, stream>>>(cnt, tki, offp, curp, tos, sot);
  gather_kernel<<<S_, 256, 0, stream>>>(hb, tos, hg);
  gemm1_kernel<<<4 * (2 * I_ / 128) * E_, 512, 0, stream>>>(hg, w1, offp, cnt, hout);   // 4mt x 88nt x 8e
  gemm2_kernel<<<4 * (H_ / 64) * E_, 512, 0, stream>>>(hout, w2, offp, cnt, dpart);     // 4mt x 32nt x 8e
  combine_kernel<<<(T_ * H_ / 4) / 256, 256, 0, stream>>>(dpart, sot, tkw, out);
}

// Round 13
// 957.777 us; speedup vs baseline: 1.1010x; 1.0145x over previous
//
#include <hip/hip_runtime.h>
#include <hip/hip_bf16.h>

typedef __bf16 bf16_t;
typedef __bf16 bf16x4 __attribute__((ext_vector_type(4)));
typedef __bf16 bf16x8 __attribute__((ext_vector_type(8)));
typedef float  f32x4  __attribute__((ext_vector_type(4)));

constexpr int T_ = 2048, H_ = 2048, I_ = 5632, E_ = 8, S_ = T_ * 2;

// ---- workspace layout (bytes) ----
constexpr size_t OFF_HB    = 0;                                   // bf16 hidden  [T][H]
constexpr size_t OFF_HOUT  = OFF_HB    + (size_t)T_ * H_ * 2;     // bf16 h       [S][I]
constexpr size_t OFF_DPART = OFF_HOUT  + (size_t)S_ * I_ * 2;     // f32 downpart [S][H]
constexpr size_t OFF_TOS   = OFF_DPART + (size_t)S_ * H_ * 4;     // int token_of_slot[S]
constexpr size_t OFF_SOT   = OFF_TOS   + (size_t)S_ * 4;          // int slot_of_tk[T*2]
constexpr size_t OFF_TKI   = OFF_SOT   + (size_t)S_ * 4;          // int topk_idx[T*2]
constexpr size_t OFF_TKW   = OFF_TKI   + (size_t)S_ * 4;          // f32 topk_w[T*2]
constexpr size_t OFF_CNT   = OFF_TKW   + (size_t)S_ * 4;          // int counts[E]
constexpr size_t OFF_OFFS  = OFF_CNT   + 64;                      // int offs[E]
constexpr size_t OFF_CUR   = OFF_OFFS  + 64;                      // int cursor[E]
constexpr size_t OFF_HG    = OFF_CUR   + 64;                      // bf16 gathered hidden [S][H] (16MB)

// async global->LDS, 16B per lane. LDS dest = wave-uniform base + lane*16 (HW).
__device__ __forceinline__ void gload16(const void* g, void* l) {
  __builtin_amdgcn_global_load_lds(
      (const __attribute__((address_space(1))) void*)g,
      (__attribute__((address_space(3))) void*)l, 16, 0, 0);
}

// asm-pinned global load: volatile + "memory" -> cannot be sunk/remat'd.
__device__ __forceinline__ void gld4(f32x4& d, const float* p) {
  asm volatile("global_load_dwordx4 %0, %1, off" : "=&v"(d) : "v"(p) : "memory");
}

__device__ __forceinline__ bf16x8 cvt8(f32x4 a, f32x4 b) {
  bf16x8 r;
  r[0]=(bf16_t)a[0]; r[1]=(bf16_t)a[1]; r[2]=(bf16_t)a[2]; r[3]=(bf16_t)a[3];
  r[4]=(bf16_t)b[0]; r[5]=(bf16_t)b[1]; r[6]=(bf16_t)b[2]; r[7]=(bf16_t)b[3];
  return r;
}

#define SBAR() do { __builtin_amdgcn_s_barrier(); __builtin_amdgcn_sched_barrier(0); } while (0)
#define WAITV(N) do { asm volatile("s_waitcnt vmcnt(" #N ")" ::: "memory"); \
                      __builtin_amdgcn_sched_barrier(0); } while (0)
#define WAITL0() do { asm volatile("s_waitcnt lgkmcnt(0)" ::: "memory"); \
                      __builtin_amdgcn_sched_barrier(0); } while (0)

// ================= router: logits, softmax, top-2, bf16 convert =================
__global__ __launch_bounds__(256)
void router_kernel(const float* __restrict__ hs, const float* __restrict__ gw,
                   int* __restrict__ tki, float* __restrict__ tkw,
                   int* __restrict__ counts, bf16_t* __restrict__ hb)
{
  const int t = blockIdx.x;
  const int tid = threadIdx.x;
  const int lane = tid & 63, wid = tid >> 6;
  const float* hrow = hs + (size_t)t * H_;
  const int c0 = tid * 8;
  float4 h0 = *(const float4*)(hrow + c0);
  float4 h1 = *(const float4*)(hrow + c0 + 4);
  bf16x8 hv;
  hv[0]=(bf16_t)h0.x; hv[1]=(bf16_t)h0.y; hv[2]=(bf16_t)h0.z; hv[3]=(bf16_t)h0.w;
  hv[4]=(bf16_t)h1.x; hv[5]=(bf16_t)h1.y; hv[6]=(bf16_t)h1.z; hv[7]=(bf16_t)h1.w;
  *(bf16x8*)(hb + (size_t)t * H_ + c0) = hv;

  float acc[E_];
  #pragma unroll
  for (int e = 0; e < E_; ++e) {
    const float* g = gw + (size_t)e * H_ + c0;
    float4 g0 = *(const float4*)(g);
    float4 g1 = *(const float4*)(g + 4);
    acc[e] = h0.x*g0.x + h0.y*g0.y + h0.z*g0.z + h0.w*g0.w
           + h1.x*g1.x + h1.y*g1.y + h1.z*g1.z + h1.w*g1.w;
  }
  #pragma unroll
  for (int e = 0; e < E_; ++e)
    #pragma unroll
    for (int o = 32; o > 0; o >>= 1)
      acc[e] += __shfl_down(acc[e], o);
  __shared__ float red[4][E_];
  if (lane == 0)
    #pragma unroll
    for (int e = 0; e < E_; ++e) red[wid][e] = acc[e];
  __syncthreads();
  if (tid == 0) {
    float l[E_];
    #pragma unroll
    for (int e = 0; e < E_; ++e) l[e] = red[0][e] + red[1][e] + red[2][e] + red[3][e];
    float m = l[0];
    #pragma unroll
    for (int e = 1; e < E_; ++e) m = fmaxf(m, l[e]);
    float p[E_]; float s = 0.f;
    #pragma unroll
    for (int e = 0; e < E_; ++e) { p[e] = __expf(l[e] - m); s += p[e]; }
    int i1 = 0;
    #pragma unroll
    for (int e = 1; e < E_; ++e) if (l[e] > l[i1]) i1 = e;
    int i2 = (i1 == 0) ? 1 : 0;
    #pragma unroll
    for (int e = 0; e < E_; ++e) if (e != i1 && l[e] > l[i2]) i2 = e;
    tki[2*t] = i1; tki[2*t+1] = i2;
    tkw[2*t] = p[i1] / s; tkw[2*t+1] = p[i2] / s;
    atomicAdd(&counts[i1], 1);
    atomicAdd(&counts[i2], 1);
  }
}

// ================= scan: expert offsets + slot lists =================
__global__ void scan_kernel(const int* __restrict__ counts, const int* __restrict__ tki,
                            int* __restrict__ offs, int* __restrict__ cursor,
                            int* __restrict__ tos, int* __restrict__ sot)
{
  if (threadIdx.x == 0) {
    int run = 0;
    for (int e = 0; e < E_; ++e) { offs[e] = run; cursor[e] = run; run += counts[e]; }
  }
  __syncthreads();
  for (int t = threadIdx.x; t < T_; t += blockDim.x) {
    #pragma unroll
    for (int k = 0; k < 2; ++k) {
      int e = tki[2*t + k];
      int s = atomicAdd(&cursor[e], 1);
      tos[s] = t;
      sot[2*t + k] = s;
    }
  }
}

// ================= gather: hg[slot] = hb[tos[slot]] =================
__global__ __launch_bounds__(256)
void gather_kernel(const bf16_t* __restrict__ hb, const int* __restrict__ tos,
                   bf16_t* __restrict__ hg)
{
  const int slot = blockIdx.x;
  const int tok  = tos[slot];
  const int c = threadIdx.x * 8;
  *(bf16x8*)(hg + (size_t)slot * H_ + c) = *(const bf16x8*)(hb + (size_t)tok * H_ + c);
}

// ================= GEMM1: hg x w1^T, dual (gate,up), fused silu*mul =================
// LDS-BW-bound fix: per-wave tile 128x64 (was 64x64) -> FLOP/LDS-byte 43 (was 32),
// 32 MFMA/step (was 16). BM=256, N-eff=256 (128 gate + 128 up cols), BK=32,
// 8 waves 2M x 4N. r12 counted-vmcnt depth-2 skeleton, 0-conflict pair-packed layouts.
// LDS: A 3x16KB + B 2x16KB = 80KB.
constexpr int G1_ABUF = 16384, G1_BBUF = 16384;
constexpr int G1_BBASE = 3 * G1_ABUF;

__global__ __launch_bounds__(512, 2)
void gemm1_kernel(const bf16_t* __restrict__ hg, const float* __restrict__ w1,
                  const int* __restrict__ offs, const int* __restrict__ counts,
                  bf16_t* __restrict__ hout)
{
  const int bid = blockIdx.x;
  const int e   = bid & 7;
  const int idx = bid >> 3;          // 4 mt x 44 nt
  const int mt  = idx & 3;
  const int nt  = idx >> 2;

  const int cnt = counts[e];
  const int m0 = mt * 256;
  if (m0 >= cnt) return;
  const int off = offs[e];
  const int n0 = nt * 128;           // gate col base (up cols same index)

  const float* Wg = w1 + (size_t)e * (2 * (size_t)I_ * H_) + (size_t)n0 * H_;

  __shared__ char smem[3 * G1_ABUF + 2 * G1_BBUF];   // 80KB

  const int tid = threadIdx.x;
  const int lane = tid & 63, wid = tid >> 6;   // 8 waves
  const int wm = wid >> 2, wn = wid & 3;       // 2M x 4N
  const int l15 = lane & 15, l4 = lane >> 4;

  // --- A staging: 16 chunks of 1KB (8 pairs x 128B); wave stages q = wid*2+{0,1}.
  const bf16_t* agp[2]; int aoff[2];
  #pragma unroll
  for (int i = 0; i < 2; ++i) {
    int q = wid * 2 + i;
    int w = (lane & 7) ^ ((lane >> 3) & 7);
    int row = 2 * (q * 8 + (lane >> 3)) + (w >> 2);
    int slot = off + m0 + row, mx = off + cnt - 1;
    if (slot > mx) slot = mx;                  // clamp pad rows (masked at store)
    agp[i]  = hg + (size_t)slot * H_ + (w & 3) * 8;
    aoff[i] = q * 1024;
  }
  auto stageA = [&](int ab, int t) {
    char* p = smem + ab * G1_ABUF;
    #pragma unroll
    for (int i = 0; i < 2; ++i) gload16(agp[i] + t * 32, p + aoff[i]);
  };

  // --- B: 256 rows (0-127 gate n0+r, 128-255 up) x 32 f32. 2 threads/row, 16 f32 each.
  // thread: row = tid>>1, f32 kbase = (tid&1)*16 -> 4 gld4 -> 2 bf16x8 writes.
  // LDS pair-packed: pair p=row>>1, sub=row&1; slot s covers 8 bf16 (k=s*8..);
  // wanted w = sub*4 + s, phys = w ^ (p&7), byte = p*128 + phys*16.
  const int brow = tid >> 1, bh = tid & 1;
  const size_t bwrow = (brow < 128) ? (size_t)brow : (size_t)(I_ + brow - 128);
  const float* bsrc = Wg + bwrow * H_ + bh * 16;
  int bOff0, bOff1;
  {
    int p = brow >> 1, sub = brow & 1;
    int w0 = sub * 4 + bh * 2, w1_ = w0 + 1;
    bOff0 = p * 128 + ((w0  ^ (p & 7)) * 16);
    bOff1 = p * 128 + ((w1_ ^ (p & 7)) * 16);
  }
  f32x4 b0a, b0b, b0c, b0d, b1a, b1b, b1c, b1d;   // two depth sets (static names)

  f32x4 accg[8][2], accu[8][2];
  #pragma unroll
  for (int mi = 0; mi < 8; ++mi)
    #pragma unroll
    for (int ni = 0; ni < 2; ++ni) {
      accg[mi][ni] = f32x4{0.f,0.f,0.f,0.f};
      accu[mi][ni] = f32x4{0.f,0.f,0.f,0.f};
    }

  const int phys = ((((l15 & 1) << 2) | l4) ^ ((l15 >> 1) & 7)) * 16;

  auto compute = [&](int ab, int blds) {
    const char* ap = smem + ab * G1_ABUF;
    const char* bp = smem + G1_BBASE + blds * G1_BBUF;
    bf16x8 bgf[2], buf2[2];
    #pragma unroll
    for (int ni = 0; ni < 2; ++ni) {
      int rg = wn * 32 + ni * 16 + l15;          // gate LDS row in [0,128)
      bgf[ni]  = *(const bf16x8*)(bp + (rg >> 1) * 128 + phys);
      buf2[ni] = *(const bf16x8*)(bp + ((rg + 128) >> 1) * 128 + phys);  // up: +64 pairs, (p+64)&7==p&7
    }
    #pragma unroll
    for (int mi = 0; mi < 8; ++mi) {
      int pr = wm * 64 + mi * 8 + (l15 >> 1);    // pair of row wm*128+mi*16+l15
      bf16x8 af = *(const bf16x8*)(ap + pr * 128 + phys);
      accg[mi][0] = __builtin_amdgcn_mfma_f32_16x16x32_bf16(af, bgf[0],  accg[mi][0], 0, 0, 0);
      accg[mi][1] = __builtin_amdgcn_mfma_f32_16x16x32_bf16(af, bgf[1],  accg[mi][1], 0, 0, 0);
      accu[mi][0] = __builtin_amdgcn_mfma_f32_16x16x32_bf16(af, buf2[0], accu[mi][0], 0, 0, 0);
      accu[mi][1] = __builtin_amdgcn_mfma_f32_16x16x32_bf16(af, buf2[1], accu[mi][1], 0, 0, 0);
    }
  };
  auto writeB = [&](int blds, f32x4& a, f32x4& b, f32x4& c, f32x4& d) {
    char* bp = smem + G1_BBASE + blds * G1_BBUF;
    *(bf16x8*)(bp + bOff0) = cvt8(a, b);
    *(bf16x8*)(bp + bOff1) = cvt8(c, d);
  };

  constexpr int NK = H_ / 32;   // 64 (even)
  // prologue: A(0),B(0),A(1),B(1); wait oldest 6 (A0x2+B0x4); publish step-0
  stageA(0, 0);
  gld4(b0a, bsrc); gld4(b0b, bsrc + 4); gld4(b0c, bsrc + 8); gld4(b0d, bsrc + 12);
  stageA(1, 1);
  gld4(b1a, bsrc + 32); gld4(b1b, bsrc + 36); gld4(b1c, bsrc + 40); gld4(b1d, bsrc + 44);
  WAITV(6);
  writeB(0, b0a, b0b, b0c, b0d);
  WAITL0();
  SBAR();

  int aR = 0, aN = 1, aW = 2;
  for (int t = 0; t < NK - 2; t += 2) {
    // even step t: issue A(t+2), B-set0 <- k(t+2); compute(t) on B-LDS0; write B-LDS1 (k t+1)
    stageA(aW, t + 2);
    { const float* s = bsrc + (t + 2) * 32;
      gld4(b0a, s); gld4(b0b, s + 4); gld4(b0c, s + 8); gld4(b0d, s + 12); }
    compute(aR, 0);
    WAITV(6);
    writeB(1, b1a, b1b, b1c, b1d);
    WAITL0();
    SBAR();
    { int tmp = aR; aR = aN; aN = aW; aW = tmp; }
    // odd step t+1
    stageA(aW, t + 3);
    { const float* s = bsrc + (t + 3) * 32;
      gld4(b1a, s); gld4(b1b, s + 4); gld4(b1c, s + 8); gld4(b1d, s + 12); }
    compute(aR, 1);
    WAITV(6);
    writeB(0, b0a, b0b, b0c, b0d);
    WAITL0();
    SBAR();
    { int tmp = aR; aR = aN; aN = aW; aW = tmp; }
  }
  compute(aR, 0);                               // step NK-2
  WAITV(0);
  writeB(1, b1a, b1b, b1c, b1d);
  WAITL0();
  SBAR();
  compute(aN, 1);                               // step NK-1

  // epilogue: silu(g)*u -> bf16 h[slot][i]   (C/D map: row=(lane>>4)*4+j, col=lane&15)
  #pragma unroll
  for (int mi = 0; mi < 8; ++mi)
    #pragma unroll
    for (int ni = 0; ni < 2; ++ni)
      #pragma unroll
      for (int j = 0; j < 4; ++j) {
        int rel = wm*128 + mi*16 + l4*4 + j;
        if (m0 + rel < cnt) {
          int col = n0 + wn*32 + ni*16 + l15;
          float g = accg[mi][ni][j];
          float u = accu[mi][ni][j];
          float hvv = (g / (1.0f + __expf(-g))) * u;
          hout[(size_t)(off + m0 + rel) * I_ + col] = (bf16_t)hvv;
        }
      }
}

// ================= GEMM2: h x w2^T -> per-slot partial (f32) =================
// BM=256, BN=128, BK=32, 8 waves 4M x 2N (wave 64x64). 256 real blocks = 1 CU round.
// B: 128 rows x 32 f32; 4 threads/row, 8 f32 each -> 2 gld4 -> 1 bf16x8 write.
constexpr int G2_ABUF = 16384, G2_BBUF = 8192;
constexpr int G2_BBASE = 3 * G2_ABUF;

__global__ __launch_bounds__(512, 2)
void gemm2_kernel(const bf16_t* __restrict__ hbuf, const float* __restrict__ w2,
                  const int* __restrict__ offs, const int* __restrict__ counts,
                  float* __restrict__ dpart)
{
  const int bid = blockIdx.x;
  const int e   = bid & 7;
  const int idx = bid >> 3;          // 4 mt x 16 nt
  const int mt  = idx & 3;
  const int nt  = idx >> 2;

  const int cnt = counts[e];
  const int m0 = mt * 256;
  if (m0 >= cnt) return;
  const int off = offs[e];
  const int n0 = nt * 128;
  const float* W = w2 + (size_t)e * ((size_t)H_ * I_) + (size_t)n0 * I_;

  __shared__ char smem[3 * G2_ABUF + 2 * G2_BBUF];   // 64KB

  const int tid = threadIdx.x;
  const int lane = tid & 63, wid = tid >> 6;
  const int wm = wid >> 1, wn = wid & 1;       // 4M x 2N
  const int l15 = lane & 15, l4 = lane >> 4;

  const bf16_t* agp[2]; int aoff[2];
  #pragma unroll
  for (int i = 0; i < 2; ++i) {
    int q = wid * 2 + i;
    int w = (lane & 7) ^ ((lane >> 3) & 7);
    int row = 2 * (q * 8 + (lane >> 3)) + (w >> 2);
    int slot = off + m0 + row, mx = off + cnt - 1;
    if (slot > mx) slot = mx;
    agp[i]  = hbuf + (size_t)slot * I_ + (w & 3) * 8;
    aoff[i] = q * 1024;
  }
  auto stageA = [&](int ab, int t) {
    char* p = smem + ab * G2_ABUF;
    #pragma unroll
    for (int i = 0; i < 2; ++i) gload16(agp[i] + t * 32, p + aoff[i]);
  };

  // B: row = tid>>2 (128 rows), slot s = tid&3 (8 f32 each)
  const int brow = tid >> 2, bs = tid & 3;
  const float* bsrc = W + (size_t)brow * I_ + bs * 8;
  int bOff;
  {
    int p = brow >> 1, sub = brow & 1;
    int w_ = sub * 4 + bs;
    bOff = p * 128 + ((w_ ^ (p & 7)) * 16);
  }
  f32x4 b0a, b0b, b1a, b1b;

  f32x4 acc[4][4];
  #pragma unroll
  for (int mi = 0; mi < 4; ++mi)
    #pragma unroll
    for (int ni = 0; ni < 4; ++ni) acc[mi][ni] = f32x4{0.f,0.f,0.f,0.f};

  const int phys = ((((l15 & 1) << 2) | l4) ^ ((l15 >> 1) & 7)) * 16;

  auto compute = [&](int ab, int blds) {
    const char* ap = smem + ab * G2_ABUF;
    const char* bp = smem + G2_BBASE + blds * G2_BBUF;
    bf16x8 bf[4];
    #pragma unroll
    for (int ni = 0; ni < 4; ++ni) {
      int r = wn * 64 + ni * 16 + l15;           // [0,128)
      bf[ni] = *(const bf16x8*)(bp + (r >> 1) * 128 + phys);
    }
    #pragma unroll
    for (int mi = 0; mi < 4; ++mi) {
      int pr = wm * 32 + mi * 8 + (l15 >> 1);    // pair of row wm*64+mi*16+l15
      bf16x8 af = *(const bf16x8*)(ap + pr * 128 + phys);
      acc[mi][0] = __builtin_amdgcn_mfma_f32_16x16x32_bf16(af, bf[0], acc[mi][0], 0, 0, 0);
      acc[mi][1] = __builtin_amdgcn_mfma_f32_16x16x32_bf16(af, bf[1], acc[mi][1], 0, 0, 0);
      acc[mi][2] = __builtin_amdgcn_mfma_f32_16x16x32_bf16(af, bf[2], acc[mi][2], 0, 0, 0);
      acc[mi][3] = __builtin_amdgcn_mfma_f32_16x16x32_bf16(af, bf[3], acc[mi][3], 0, 0, 0);
    }
  };
  auto writeB = [&](int blds, f32x4& a, f32x4& b) {
    *(bf16x8*)(smem + G2_BBASE + blds * G2_BBUF + bOff) = cvt8(a, b);
  };

  constexpr int NK = I_ / 32;   // 176 (even)
  stageA(0, 0);
  gld4(b0a, bsrc); gld4(b0b, bsrc + 4);
  stageA(1, 1);
  gld4(b1a, bsrc + 32); gld4(b1b, bsrc + 36);
  WAITV(4);                                    // A0x2 + B0x2 landed
  writeB(0, b0a, b0b);
  WAITL0();
  SBAR();

  int aR = 0, aN = 1, aW = 2;
  for (int t = 0; t < NK - 2; t += 2) {
    stageA(aW, t + 2);
    { const float* s = bsrc + (t + 2) * 32; gld4(b0a, s); gld4(b0b, s + 4); }
    compute(aR, 0);
    WAITV(4);
    writeB(1, b1a, b1b);
    WAITL0();
    SBAR();
    { int tmp = aR; aR = aN; aN = aW; aW = tmp; }
    stageA(aW, t + 3);
    { const float* s = bsrc + (t + 3) * 32; gld4(b1a, s); gld4(b1b, s + 4); }
    compute(aR, 1);
    WAITV(4);
    writeB(0, b0a, b0b);
    WAITL0();
    SBAR();
    { int tmp = aR; aR = aN; aN = aW; aW = tmp; }
  }
  compute(aR, 0);
  WAITV(0);
  writeB(1, b1a, b1b);
  WAITL0();
  SBAR();
  compute(aN, 1);

  #pragma unroll
  for (int mi = 0; mi < 4; ++mi)
    #pragma unroll
    for (int ni = 0; ni < 4; ++ni)
      #pragma unroll
      for (int j = 0; j < 4; ++j) {
        int rel = wm*64 + mi*16 + l4*4 + j;
        if (m0 + rel < cnt) {
          int col = n0 + wn*64 + ni*16 + l15;
          dpart[(size_t)(off + m0 + rel) * H_ + col] = acc[mi][ni][j];
        }
      }
}

// ================= combine: out[t] = w0*d[s0] + w1*d[s1] =================
__global__ __launch_bounds__(256)
void combine_kernel(const float* __restrict__ dpart, const int* __restrict__ sot,
                    const float* __restrict__ tkw, float* __restrict__ out)
{
  int idx = blockIdx.x * 256 + threadIdx.x;     // T*H/4 total
  int t = idx >> 9;                              // H/4 = 512
  int c = (idx & 511) * 4;
  float wA = tkw[2*t], wB = tkw[2*t+1];
  int sA = sot[2*t], sB = sot[2*t+1];
  float4 a = *(const float4*)(dpart + (size_t)sA * H_ + c);
  float4 b = *(const float4*)(dpart + (size_t)sB * H_ + c);
  float4 o;
  o.x = wA*a.x + wB*b.x; o.y = wA*a.y + wB*b.y;
  o.z = wA*a.z + wB*b.z; o.w = wA*a.w + wB*b.w;
  *(float4*)(out + (size_t)t * H_ + c) = o;
}

extern "C" void kernel_launch(void* const* d_in, const int* in_sizes, int n_in,
                              void* d_out, int out_size, void* d_ws, size_t ws_size,
                              hipStream_t stream) {
  const float* hs = (const float*)d_in[0];
  const float* gw = (const float*)d_in[1];
  const float* w1 = (const float*)d_in[2];
  const float* w2 = (const float*)d_in[3];
  float* out = (float*)d_out;
  char* ws = (char*)d_ws;

  bf16_t* hb    = (bf16_t*)(ws + OFF_HB);
  bf16_t* hout  = (bf16_t*)(ws + OFF_HOUT);
  float*  dpart = (float*) (ws + OFF_DPART);
  int*    tos   = (int*)   (ws + OFF_TOS);
  int*    sot   = (int*)   (ws + OFF_SOT);
  int*    tki   = (int*)   (ws + OFF_TKI);
  float*  tkw   = (float*) (ws + OFF_TKW);
  int*    cnt   = (int*)   (ws + OFF_CNT);
  int*    offp  = (int*)   (ws + OFF_OFFS);
  int*    curp  = (int*)   (ws + OFF_CUR);
  bf16_t* hg    = (bf16_t*)(ws + OFF_HG);

  hipMemsetAsync(ws + OFF_CNT, 0, 64, stream);   // zero expert counts each call

  router_kernel<<<T_, 256, 0, stream>>>(hs, gw, tki, tkw, cnt, hb);
  scan_kernel<<<1, 256, 0, stream>>>(cnt, tki, offp, curp, tos, sot);
  gather_kernel<<<S_, 256, 0, stream>>>(hb, tos, hg);
  gemm1_kernel<<<4 * (I_ / 128) * E_, 512, 0, stream>>>(hg, w1, offp, cnt, hout);     // 4mt x 44nt x 8e
  gemm2_kernel<<<4 * (H_ / 128) * E_, 512, 0, stream>>>(hout, w2, offp, cnt, dpart);  // 4mt x 16nt x 8e
  combine_kernel<<<(T_ * H_ / 4) / 256, 256, 0, stream>>>(dpart, sot, tkw, out);
}